// Round 5
// baseline (1135.043 us; speedup 1.0000x reference)
//
#include <hip/hip_runtime.h>
#include <hip/hip_bf16.h>

#define VOCAB   65
#define SQRT_C  5.656854249492381f
#define BATCHES 65536
#define ROWS    (BATCHES * 8)
#define TABSZ   (8 * VOCAB * 32)       // 16640 floats per q/k/v table
#define PAIRS   (BATCHES / 2)          // 32768 batch-pairs (16 rows each)
#define NBLOCKS (PAIRS / 4)            // 8192 one-shot blocks, 4 waves each
#define NFRAG   448                    // 7 fragment classes x 64 lanes

typedef __attribute__((ext_vector_type(8))) short  short8;   // 8 bf16 = 4 VGPRs
typedef __attribute__((ext_vector_type(4))) float  float4v;  // MFMA C/D

__device__ __forceinline__ void wave_fence() {
    __asm__ volatile("s_waitcnt lgkmcnt(0)" ::: "memory");
}
__device__ __forceinline__ short bfbits(float f) {
    __hip_bfloat16 h = __float2bfloat16(f);
    return *reinterpret_cast<short*>(&h);
}

// ---------------------------------------------------------------------------
// Kernel 1: (a) q/k/v tables over the 520 distinct (t, token) combos,
// tab[(t*65+tok)*32 + h*8 + d], sqrt(C) folded into qtab (faithful bug);
// (b) lane-indexed bf16 weight-fragment table (7 classes x 64 lanes x short8)
// so the fused kernel's prologue is 7 coalesced b128 loads instead of ~56
// scattered loads + converts; (c) zero-init of 16 loss slots + done counter.
// ---------------------------------------------------------------------------
__global__ void qkv_table_kernel(const float* __restrict__ tok_emb,
                                 const float* __restrict__ pos_emb,
                                 const float* __restrict__ Wq,
                                 const float* __restrict__ Wk,
                                 const float* __restrict__ Wv,
                                 const float* __restrict__ W_mlp,
                                 const float* __restrict__ W_lm,
                                 float* __restrict__ qtab,
                                 float* __restrict__ ktab,
                                 float* __restrict__ vtab,
                                 float* __restrict__ frag_tab,
                                 float* __restrict__ loss_slots,
                                 unsigned* __restrict__ done_ctr) {
    int o = blockIdx.x * 256 + threadIdx.x;
    if (o < 16) loss_slots[o * 16] = 0.f;
    if (o == 16) done_ctr[0] = 0u;

    if (o < 3 * TABSZ) {
        int table = o / TABSZ;
        int r = o - table * TABSZ;
        int pair = r >> 5;
        int cd = r & 31;
        int t = pair / VOCAB;
        int tok = pair - t * VOCAB;
        int h = cd >> 3, d = cd & 7;
        const float* W = (table == 0) ? Wq : (table == 1) ? Wk : Wv;
        float acc = 0.f;
        #pragma unroll
        for (int c = 0; c < 32; ++c) {
            float xc = tok_emb[tok * 32 + c] + pos_emb[t * 32 + c];
            acc += xc * W[h * 256 + c * 8 + d];
        }
        if (table == 0) acc *= SQRT_C;   // faithful bug: scores * sqrt(C)
        float* tab = (table == 0) ? qtab : (table == 1) ? ktab : vtab;
        tab[r] = acc;
    } else if (o < 3 * TABSZ + NFRAG) {
        int f = o - 3 * TABSZ;
        int cls = f >> 6, lane = f & 63;
        int q4l = lane >> 4, nl = lane & 15;
        short8 v;
        #pragma unroll
        for (int j = 0; j < 8; ++j) {
            int k = q4l * 8 + j;
            if (cls < 2)       v[j] = bfbits(W_mlp[k * 32 + cls * 16 + nl]);
            else if (cls < 6)  v[j] = bfbits(W_lm[k * VOCAB + (cls - 2) * 16 + nl]);
            else               v[j] = (nl == 0) ? bfbits(W_lm[k * VOCAB + 64]) : (short)0;
        }
        ((short8*)frag_tab)[f] = v;
    }
}

// ---------------------------------------------------------------------------
// Kernel 2: throughput mode.  8192 one-shot blocks x 4 waves; each wave owns
// exactly ONE batch-pair (16 logit rows).  No loop, no pipeline state: chains
// are short and independent, blocks retire fast, dispatcher backfills.
//  - Clean memory shape (measured R0/R4: FETCH 3MB, WRITE ~logits):
//    per-lane distinct-address gather -> LDS -> attention reads broadcast.
//  - Prologue: 7 coalesced b128 fragment loads (precomputed in kernel 1).
//  - Scattered register logit stores (clean in both low-occupancy rounds).
//  - Loss: 16 line-padded atomic slots + last-block finalize.
// ---------------------------------------------------------------------------
__global__ __launch_bounds__(256, 7) void fused_kernel(
        const int* __restrict__ idx, const int* __restrict__ targets,
        const float* __restrict__ qtab, const float* __restrict__ ktab,
        const float* __restrict__ vtab,
        const float* __restrict__ frag_tab,
        const float* __restrict__ b_mlp,
        const float* __restrict__ b_lm,
        float* __restrict__ out_logits,
        float* __restrict__ loss_slots,
        unsigned* __restrict__ done_ctr,
        float* __restrict__ out_loss) {
    // per-wave K/V: [grp=h*2+b2][s][d], grp-stride 68 words
    __shared__ __align__(16) float sK[4][544];
    __shared__ __align__(16) float sV[4][544];
    // per-wave x3 bf16 [row][ch], row-stride 40 shorts (80B, 16B-aligned)
    __shared__ __align__(16) unsigned short sX3[4][640];
    __shared__ float wsum[4];

    const int tid = threadIdx.x;
    const int w = tid >> 6, l = tid & 63;
    const int q4 = l >> 4;        // MFMA quad
    const int n  = l & 15;        // MFMA col-lane / A-row
    const int t  = l & 7, b2 = (l >> 3) & 1, h = q4;   // attention identity

    const int pb = blockIdx.x * 4 + w;

    // ---- tokens / targets (one 64B line per pair) ----
    int tokv = 0, tgv = 0;
    if (l < 16) { tokv = idx[pb * 16 + l]; tgv = targets[pb * 16 + l]; }

    // ---- prologue: 7 coalesced fragment loads + 7 bias scalars ----
    const short8* ftab = (const short8*)frag_tab;
    short8 wmf[2], wlf[4], wlf4;
    wmf[0] = ftab[l];        wmf[1] = ftab[64 + l];
    #pragma unroll
    for (int c = 0; c < 4; ++c) wlf[c] = ftab[(2 + c) * 64 + l];
    wlf4 = ftab[6 * 64 + l];
    float bmc[2], blc[4];
    #pragma unroll
    for (int c = 0; c < 2; ++c) bmc[c] = b_mlp[c * 16 + n];
    #pragma unroll
    for (int c = 0; c < 4; ++c) blc[c] = b_lm[c * 16 + n];
    const float bl64 = b_lm[64];
    const float4v zf = {0.f, 0.f, 0.f, 0.f};

    // ---- gather K/V into LDS (per-lane distinct addresses, 2 f4 each) ----
    {
        int c1 = l + 64;
        int s0 = (l >> 1) & 7, g0 = l >> 4, d2 = l & 1, g1 = c1 >> 4;
        int ts0 = __shfl(tokv, (g0 & 1) * 8 + s0);
        int ts1 = __shfl(tokv, (g1 & 1) * 8 + s0);
        int ga0 = (s0 * VOCAB + ts0) * 32 + (g0 >> 1) * 8 + d2 * 4;
        int ga1 = (s0 * VOCAB + ts1) * 32 + (g1 >> 1) * 8 + d2 * 4;
        int la0 = g0 * 68 + s0 * 8 + d2 * 4;
        int la1 = g1 * 68 + s0 * 8 + d2 * 4;
        *(float4*)(&sK[w][la0]) = *(const float4*)(ktab + ga0);
        *(float4*)(&sK[w][la1]) = *(const float4*)(ktab + ga1);
        *(float4*)(&sV[w][la0]) = *(const float4*)(vtab + ga0);
        *(float4*)(&sV[w][la1]) = *(const float4*)(vtab + ga1);
    }
    // own q row (qtab already carries * sqrt(C))
    const int tok_t = __shfl(tokv, b2 * 8 + t);
    const float* qp = qtab + (t * VOCAB + tok_t) * 32 + h * 8;
    const float4 q0 = *(const float4*)(qp);
    const float4 q1 = *(const float4*)(qp + 4);
    // targets for my 4 epilogue rows
    int tgrc[4];
    #pragma unroll
    for (int i = 0; i < 4; ++i) tgrc[i] = __shfl(tgv, q4 * 4 + i);
    wave_fence();

    // ---- attention (fp32): lane (b2,h,t); out lands in MFMA A-layout ----
    const float* kb = &sK[w][(h * 2 + b2) * 68];
    const float* vb = &sV[w][(h * 2 + b2) * 68];
    float sc[8], m = -1e30f;
    #pragma unroll
    for (int s = 0; s < 8; ++s) {
        float4 k0 = *(const float4*)(kb + s * 8);
        float4 k1 = *(const float4*)(kb + s * 8 + 4);
        float d = q0.x * k0.x + q0.y * k0.y + q0.z * k0.z + q0.w * k0.w
                + q1.x * k1.x + q1.y * k1.y + q1.z * k1.z + q1.w * k1.w;
        sc[s] = d;
        if (s <= t) m = fmaxf(m, d);
    }
    float p[8], sum = 0.f;
    #pragma unroll
    for (int s = 0; s < 8; ++s) {
        p[s] = (s <= t) ? __expf(sc[s] - m) : 0.f;
        sum += p[s];
    }
    float inv = 1.f / sum;
    float o[8];
    #pragma unroll
    for (int d = 0; d < 8; ++d) o[d] = 0.f;
    #pragma unroll
    for (int s = 0; s < 8; ++s) {
        float4 v0 = *(const float4*)(vb + s * 8);
        float4 v1 = *(const float4*)(vb + s * 8 + 4);
        o[0] += p[s] * v0.x; o[1] += p[s] * v0.y;
        o[2] += p[s] * v0.z; o[3] += p[s] * v0.w;
        o[4] += p[s] * v1.x; o[5] += p[s] * v1.y;
        o[6] += p[s] * v1.z; o[7] += p[s] * v1.w;
    }
    short8 a2;
    #pragma unroll
    for (int d = 0; d < 8; ++d) a2[d] = bfbits(o[d] * inv);

    // ---- MLP: x3 = relu(x2 @ W_mlp + b), 2 MFMAs ----
    float4v d0 = __builtin_amdgcn_mfma_f32_16x16x32_bf16(a2, wmf[0], zf, 0, 0, 0);
    float4v d1 = __builtin_amdgcn_mfma_f32_16x16x32_bf16(a2, wmf[1], zf, 0, 0, 0);
    #pragma unroll
    for (int i = 0; i < 4; ++i) {
        int row = q4 * 4 + i;
        sX3[w][row * 40 + n]      = (unsigned short)bfbits(fmaxf(d0[i] + bmc[0], 0.f));
        sX3[w][row * 40 + 16 + n] = (unsigned short)bfbits(fmaxf(d1[i] + bmc[1], 0.f));
    }
    wave_fence();
    // C->A transpose via LDS: one b128 read
    short8 a3 = *(const short8*)(&sX3[w][n * 40 + q4 * 8]);

    // ---- logits: 5 MFMAs (cols 0..63 + padded col-64 fragment) ----
    float4v Lc[4];
    #pragma unroll
    for (int c = 0; c < 4; ++c)
        Lc[c] = __builtin_amdgcn_mfma_f32_16x16x32_bf16(a3, wlf[c], zf, 0, 0, 0);
    float4v L64 = __builtin_amdgcn_mfma_f32_16x16x32_bf16(a3, wlf4, zf, 0, 0, 0);

    // ---- bias + scattered store + sum-exp + inline target pick ----
    float loss_local = 0.f;
    size_t rb = (size_t)pb * 16;
    float part[4] = {0.f, 0.f, 0.f, 0.f};
    #pragma unroll
    for (int c = 0; c < 4; ++c) {
        #pragma unroll
        for (int i = 0; i < 4; ++i) {
            float Lv = Lc[c][i] + blc[c];
            out_logits[(rb + q4 * 4 + i) * VOCAB + c * 16 + n] = Lv;
            part[i] += __expf(Lv);
            if (c * 16 + n == tgrc[i]) loss_local -= Lv;   // 1 lane/row
        }
    }
    if (n == 0) {
        #pragma unroll
        for (int i = 0; i < 4; ++i) {
            float Lv = L64[i] + bl64;
            out_logits[(rb + q4 * 4 + i) * VOCAB + 64] = Lv;
            part[i] += __expf(Lv);
            if (tgrc[i] == 64) loss_local -= Lv;
        }
    }
    #pragma unroll
    for (int off = 1; off < 16; off <<= 1) {
        #pragma unroll
        for (int i = 0; i < 4; ++i) part[i] += __shfl_xor(part[i], off);
    }
    if (n == 0)
        loss_local += __logf(part[0]) + __logf(part[1])
                    + __logf(part[2]) + __logf(part[3]);

    // ---- block loss -> slotted atomic -> last-block finalize ----
    #pragma unroll
    for (int off = 1; off < 64; off <<= 1) loss_local += __shfl_xor(loss_local, off);
    if (l == 0) wsum[w] = loss_local;
    __syncthreads();
    if (tid == 0) {
        atomicAdd(&loss_slots[(blockIdx.x & 15) * 16],
                  wsum[0] + wsum[1] + wsum[2] + wsum[3]);
        __threadfence();
        unsigned done = atomicAdd(done_ctr, 1u);
        if (done == NBLOCKS - 1) {
            __threadfence();
            float tot = 0.f;
            #pragma unroll
            for (int s = 0; s < 16; ++s)
                tot += atomicAdd(&loss_slots[s * 16], 0.f);   // coherent read
            out_loss[0] = tot * (1.f / (float)ROWS);
        }
    }
}

extern "C" void kernel_launch(void* const* d_in, const int* in_sizes, int n_in,
                              void* d_out, int out_size, void* d_ws, size_t ws_size,
                              hipStream_t stream) {
    const int* idx        = (const int*)d_in[0];
    const int* targets    = (const int*)d_in[1];
    const float* tok_emb  = (const float*)d_in[2];
    const float* pos_emb  = (const float*)d_in[3];
    const float* Wq       = (const float*)d_in[4];
    const float* Wk       = (const float*)d_in[5];
    const float* Wv       = (const float*)d_in[6];
    const float* W_mlp    = (const float*)d_in[7];
    const float* b_mlp    = (const float*)d_in[8];
    const float* W_lm     = (const float*)d_in[9];
    const float* b_lm     = (const float*)d_in[10];
    float* out            = (float*)d_out;

    float* ws         = (float*)d_ws;
    float* loss_slots = ws;                       // 16 slots, 64B apart
    unsigned* ctr     = (unsigned*)(ws + 256);
    float* frag       = ws + 272;                 // 448 short8 = 1792 floats
    float* qtab       = ws + 272 + 1792;
    float* ktab       = qtab + TABSZ;
    float* vtab       = ktab + TABSZ;
    float* out_loss   = out + (size_t)ROWS * VOCAB;

    qkv_table_kernel<<<(3 * TABSZ + NFRAG + 255) / 256, 256, 0, stream>>>(
        tok_emb, pos_emb, Wq, Wk, Wv, W_mlp, W_lm,
        qtab, ktab, vtab, frag, loss_slots, ctr);

    fused_kernel<<<NBLOCKS, 256, 0, stream>>>(
        idx, targets, qtab, ktab, vtab, frag, b_mlp, b_lm,
        out, loss_slots, ctr, out_loss);
}

// Round 6
// 363.760 us; speedup vs baseline: 3.1203x; 3.1203x over previous
//
#include <hip/hip_runtime.h>
#include <hip/hip_bf16.h>

#define VOCAB   65
#define SQRT_C  5.656854249492381f
#define BATCHES 65536
#define ROWS    (BATCHES * 8)
#define TABSZ   (8 * VOCAB * 32)       // 16640 floats per q/k/v table
#define PAIRS   (BATCHES / 2)          // 32768 batch-pairs (16 rows each)
#define NBLOCKS 2048
#define NWAVES  (NBLOCKS * 4)
#define NFRAG   448                    // 7 fragment classes x 64 lanes

typedef __attribute__((ext_vector_type(8))) short  short8;   // 8 bf16 = 4 VGPRs
typedef __attribute__((ext_vector_type(4))) float  float4v;  // MFMA C/D

__device__ __forceinline__ void wave_fence() {
    __asm__ volatile("s_waitcnt lgkmcnt(0)" ::: "memory");
}
__device__ __forceinline__ short bfbits(float f) {
    __hip_bfloat16 h = __float2bfloat16(f);
    return *reinterpret_cast<short*>(&h);
}

// ---------------------------------------------------------------------------
// Kernel 1: (a) q/k/v tables over the 520 distinct (t, token) combos,
// tab[(t*65+tok)*32 + h*8 + d], sqrt(C) folded into qtab (faithful bug);
// (b) lane-indexed bf16 weight-fragment table (7 classes x 64 lanes x short8)
// so the fused kernel's prologue is 7 coalesced b128 loads; (c) loss init.
// NO fences anywhere: kernel-boundary release handles visibility.
// ---------------------------------------------------------------------------
__global__ void qkv_table_kernel(const float* __restrict__ tok_emb,
                                 const float* __restrict__ pos_emb,
                                 const float* __restrict__ Wq,
                                 const float* __restrict__ Wk,
                                 const float* __restrict__ Wv,
                                 const float* __restrict__ W_mlp,
                                 const float* __restrict__ W_lm,
                                 float* __restrict__ qtab,
                                 float* __restrict__ ktab,
                                 float* __restrict__ vtab,
                                 float* __restrict__ frag_tab,
                                 float* __restrict__ loss_acc) {
    int o = blockIdx.x * 256 + threadIdx.x;
    if (o == 0) loss_acc[0] = 0.f;

    if (o < 3 * TABSZ) {
        int table = o / TABSZ;
        int r = o - table * TABSZ;
        int pair = r >> 5;
        int cd = r & 31;
        int t = pair / VOCAB;
        int tok = pair - t * VOCAB;
        int h = cd >> 3, d = cd & 7;
        const float* W = (table == 0) ? Wq : (table == 1) ? Wk : Wv;
        float acc = 0.f;
        #pragma unroll
        for (int c = 0; c < 32; ++c) {
            float xc = tok_emb[tok * 32 + c] + pos_emb[t * 32 + c];
            acc += xc * W[h * 256 + c * 8 + d];
        }
        if (table == 0) acc *= SQRT_C;   // faithful bug: scores * sqrt(C)
        float* tab = (table == 0) ? qtab : (table == 1) ? ktab : vtab;
        tab[r] = acc;
    } else if (o < 3 * TABSZ + NFRAG) {
        int f = o - 3 * TABSZ;
        int cls = f >> 6, lane = f & 63;
        int q4l = lane >> 4, nl = lane & 15;
        short8 v;
        #pragma unroll
        for (int j = 0; j < 8; ++j) {
            int k = q4l * 8 + j;
            if (cls < 2)       v[j] = bfbits(W_mlp[k * 32 + cls * 16 + nl]);
            else if (cls < 6)  v[j] = bfbits(W_lm[k * VOCAB + (cls - 2) * 16 + nl]);
            else               v[j] = (nl == 0) ? bfbits(W_lm[k * VOCAB + 64]) : (short)0;
        }
        ((short8*)frag_tab)[f] = v;
    }
}

// ---------------------------------------------------------------------------
// Kernel 2: round-0 structure (measured clean+fastest: 188us, FETCH 3MB,
// WRITE 133MB).  4 independent waves per block; each wave owns one batch-pair
// (16 logit rows) per iteration, 4 iterations.  Deltas vs round 0:
//  - NO __threadfence / in-kernel finalize: on gfx950 a device-scope fence
//    writes back the XCD's dirty L2, flushing other blocks' partially
//    assembled logit lines -> RMW amplification (R2/R3/R5: 430-588MB writes
//    for a 136MB output).  Loss finalized by a separate 1-thread kernel.
//  - Inline target-logit extraction (no b6 gather + MFMA)     [R4-proven]
//  - sqrt(C) folded into qtab                                  [R4-proven]
//  - frag-table prologue: 7 coalesced b128 loads               [R5-proven]
//  - next-iteration token/target prefetch (~2 VGPR)            [new]
// ---------------------------------------------------------------------------
__global__ __launch_bounds__(256) void fused_kernel(
        const int* __restrict__ idx, const int* __restrict__ targets,
        const float* __restrict__ qtab, const float* __restrict__ ktab,
        const float* __restrict__ vtab,
        const float* __restrict__ frag_tab,
        const float* __restrict__ b_mlp,
        const float* __restrict__ b_lm,
        float* __restrict__ out_logits,
        float* __restrict__ loss_acc) {
    // per-wave K/V: [grp=h*2+b2][s][d], grp-stride 68 words (conflict-free
    // 8-group broadcast: 68%32=4 -> groups start 4 banks apart)
    __shared__ __align__(16) float sK[4][544];
    __shared__ __align__(16) float sV[4][544];
    // per-wave x3 bf16 [row][ch], row-stride 40 shorts (80B, 16B-aligned)
    __shared__ __align__(16) unsigned short sX3[4][640];

    const int tid = threadIdx.x;
    const int w = tid >> 6, l = tid & 63;
    const int q4 = l >> 4;        // MFMA quad
    const int n  = l & 15;        // MFMA col-lane / A-row
    const int t  = l & 7, b2 = (l >> 3) & 1, h = q4;   // attention identity

    // ---- prologue: 7 coalesced fragment loads + bias scalars ----
    const short8* ftab = (const short8*)frag_tab;
    short8 wmf[2], wlf[4], wlf4;
    wmf[0] = ftab[l];        wmf[1] = ftab[64 + l];
    #pragma unroll
    for (int c = 0; c < 4; ++c) wlf[c] = ftab[(2 + c) * 64 + l];
    wlf4 = ftab[6 * 64 + l];
    float bmc[2], blc[4];
    #pragma unroll
    for (int c = 0; c < 2; ++c) bmc[c] = b_mlp[c * 16 + n];
    #pragma unroll
    for (int c = 0; c < 4; ++c) blc[c] = b_lm[c * 16 + n];
    const float bl64 = b_lm[64];
    const float4v zf = {0.f, 0.f, 0.f, 0.f};

    float loss_local = 0.f;

    int pb = blockIdx.x * 4 + w;
    int tokv = 0, tgv = 0;
    if (l < 16) { tokv = idx[pb * 16 + l]; tgv = targets[pb * 16 + l]; }

    for (; pb < PAIRS; pb += NWAVES) {
        // ---- gather K/V into LDS: 2 float4 chunks per table per lane ----
        #pragma unroll
        for (int half = 0; half < 2; ++half) {
            int c = l + half * 64;
            int d2 = c & 1, s = (c >> 1) & 7, grp = c >> 4;   // grp 0..7
            int b2g = grp & 1, hg = grp >> 1;
            int tok_s = __shfl(tokv, b2g * 8 + s);
            int gaddr = (s * VOCAB + tok_s) * 32 + hg * 8 + d2 * 4;
            int laddr = grp * 68 + s * 8 + d2 * 4;
            *(float4*)(&sK[w][laddr]) = *(const float4*)(ktab + gaddr);
            *(float4*)(&sV[w][laddr]) = *(const float4*)(vtab + gaddr);
        }
        // own q row straight from global (L2-resident table; pre-scaled)
        int tok_t = __shfl(tokv, b2 * 8 + t);
        const float* qp = qtab + (t * VOCAB + tok_t) * 32 + h * 8;
        const float4 q0 = *(const float4*)(qp);
        const float4 q1 = *(const float4*)(qp + 4);
        // targets for my 4 epilogue rows (tgv lanes 0..15)
        int tgrc[4];
        #pragma unroll
        for (int i = 0; i < 4; ++i) tgrc[i] = __shfl(tgv, q4 * 4 + i);

        // ---- prefetch next iteration's tokens/targets (hidden here) ----
        const int pbn = pb + NWAVES;
        int tokv_n = 0, tgv_n = 0;
        if (pbn < PAIRS && l < 16) {
            tokv_n = idx[pbn * 16 + l];
            tgv_n  = targets[pbn * 16 + l];
        }
        wave_fence();

        // ---- attention (fp32): lane (b2,h,t); out lands in A-layout ----
        const float* kb = &sK[w][(h * 2 + b2) * 68];
        const float* vb = &sV[w][(h * 2 + b2) * 68];
        float sc[8], m = -1e30f;
        #pragma unroll
        for (int s = 0; s < 8; ++s) {
            float4 k0 = *(const float4*)(kb + s * 8);
            float4 k1 = *(const float4*)(kb + s * 8 + 4);
            float d = q0.x * k0.x + q0.y * k0.y + q0.z * k0.z + q0.w * k0.w
                    + q1.x * k1.x + q1.y * k1.y + q1.z * k1.z + q1.w * k1.w;
            sc[s] = d;                   // qtab already carries * sqrt(C)
            if (s <= t) m = fmaxf(m, d);
        }
        float p[8], sum = 0.f;
        #pragma unroll
        for (int s = 0; s < 8; ++s) {
            p[s] = (s <= t) ? __expf(sc[s] - m) : 0.f;
            sum += p[s];
        }
        float inv = 1.f / sum;
        float o[8];
        #pragma unroll
        for (int d = 0; d < 8; ++d) o[d] = 0.f;
        #pragma unroll
        for (int s = 0; s < 8; ++s) {
            float4 v0 = *(const float4*)(vb + s * 8);
            float4 v1 = *(const float4*)(vb + s * 8 + 4);
            o[0] += p[s] * v0.x; o[1] += p[s] * v0.y;
            o[2] += p[s] * v0.z; o[3] += p[s] * v0.w;
            o[4] += p[s] * v1.x; o[5] += p[s] * v1.y;
            o[6] += p[s] * v1.z; o[7] += p[s] * v1.w;
        }
        short8 a2;
        #pragma unroll
        for (int d = 0; d < 8; ++d) a2[d] = bfbits(o[d] * inv);

        // ---- MLP: x3 = relu(x2 @ W_mlp + b), 2 MFMAs ----
        float4v d0 = __builtin_amdgcn_mfma_f32_16x16x32_bf16(a2, wmf[0], zf, 0, 0, 0);
        float4v d1 = __builtin_amdgcn_mfma_f32_16x16x32_bf16(a2, wmf[1], zf, 0, 0, 0);
        #pragma unroll
        for (int i = 0; i < 4; ++i) {
            int row = q4 * 4 + i;
            sX3[w][row * 40 + n]      = (unsigned short)bfbits(fmaxf(d0[i] + bmc[0], 0.f));
            sX3[w][row * 40 + 16 + n] = (unsigned short)bfbits(fmaxf(d1[i] + bmc[1], 0.f));
        }
        wave_fence();
        // C->A transpose via LDS: one b128 read
        short8 a3 = *(const short8*)(&sX3[w][n * 40 + q4 * 8]);

        // ---- logits: 5 MFMAs (cols 0..63 + padded col-64 fragment) ----
        float4v Lc[4];
        #pragma unroll
        for (int c = 0; c < 4; ++c)
            Lc[c] = __builtin_amdgcn_mfma_f32_16x16x32_bf16(a3, wlf[c], zf, 0, 0, 0);
        float4v L64 = __builtin_amdgcn_mfma_f32_16x16x32_bf16(a3, wlf4, zf, 0, 0, 0);

        // ---- bias + scattered store + sum-exp + inline target pick ----
        size_t rb = (size_t)pb * 16;
        float part[4] = {0.f, 0.f, 0.f, 0.f};
        #pragma unroll
        for (int c = 0; c < 4; ++c) {
            #pragma unroll
            for (int i = 0; i < 4; ++i) {
                float Lv = Lc[c][i] + blc[c];
                out_logits[(rb + q4 * 4 + i) * VOCAB + c * 16 + n] = Lv;
                part[i] += __expf(Lv);
                if (c * 16 + n == tgrc[i]) loss_local -= Lv;   // 1 lane/row
            }
        }
        if (n == 0) {
            #pragma unroll
            for (int i = 0; i < 4; ++i) {
                float Lv = L64[i] + bl64;
                out_logits[(rb + q4 * 4 + i) * VOCAB + 64] = Lv;
                part[i] += __expf(Lv);
                if (tgrc[i] == 64) loss_local -= Lv;
            }
        }
        #pragma unroll
        for (int off = 1; off < 16; off <<= 1) {
            #pragma unroll
            for (int i = 0; i < 4; ++i) part[i] += __shfl_xor(part[i], off);
        }
        if (n == 0)
            loss_local += __logf(part[0]) + __logf(part[1])
                        + __logf(part[2]) + __logf(part[3]);

        // rotate prefetched tokens
        tokv = tokv_n; tgv = tgv_n;
    }

    #pragma unroll
    for (int off = 1; off < 64; off <<= 1) loss_local += __shfl_xor(loss_local, off);
    if (l == 0) atomicAdd(loss_acc, loss_local);
}

__global__ void finalize_loss(const float* __restrict__ acc,
                              float* __restrict__ out) {
    out[0] = acc[0] * (1.f / (float)ROWS);
}

extern "C" void kernel_launch(void* const* d_in, const int* in_sizes, int n_in,
                              void* d_out, int out_size, void* d_ws, size_t ws_size,
                              hipStream_t stream) {
    const int* idx        = (const int*)d_in[0];
    const int* targets    = (const int*)d_in[1];
    const float* tok_emb  = (const float*)d_in[2];
    const float* pos_emb  = (const float*)d_in[3];
    const float* Wq       = (const float*)d_in[4];
    const float* Wk       = (const float*)d_in[5];
    const float* Wv       = (const float*)d_in[6];
    const float* W_mlp    = (const float*)d_in[7];
    const float* b_mlp    = (const float*)d_in[8];
    const float* W_lm     = (const float*)d_in[9];
    const float* b_lm     = (const float*)d_in[10];
    float* out            = (float*)d_out;

    float* ws        = (float*)d_ws;
    float* loss_ptr  = ws;
    float* frag      = ws + 16;                    // 448 short8 = 1792 floats
    float* qtab      = frag + 1792;
    float* ktab      = qtab + TABSZ;
    float* vtab      = ktab + TABSZ;
    float* out_loss  = out + (size_t)ROWS * VOCAB;

    qkv_table_kernel<<<(3 * TABSZ + NFRAG + 255) / 256, 256, 0, stream>>>(
        tok_emb, pos_emb, Wq, Wk, Wv, W_mlp, W_lm,
        qtab, ktab, vtab, frag, loss_ptr);

    fused_kernel<<<NBLOCKS, 256, 0, stream>>>(
        idx, targets, qtab, ktab, vtab, frag, b_mlp, b_lm, out, loss_ptr);

    finalize_loss<<<1, 1, 0, stream>>>(loss_ptr, out_loss);
}

// Round 7
// 336.513 us; speedup vs baseline: 3.3730x; 1.0810x over previous
//
#include <hip/hip_runtime.h>
#include <hip/hip_bf16.h>

#define VOCAB   65
#define SQRT_C  5.656854249492381f
#define BATCHES 65536
#define ROWS    (BATCHES * 8)
#define TABSZ   (8 * VOCAB * 32)       // 16640 floats per q/k/v table
#define PAIRS   (BATCHES / 2)          // 32768 batch-pairs (16 rows each)
#define NBLOCKS (PAIRS / 4)            // 8192 one-shot blocks, 4 waves each
#define NFRAG   448                    // 7 fragment classes x 64 lanes

typedef __attribute__((ext_vector_type(8))) short  short8;   // 8 bf16 = 4 VGPRs
typedef __attribute__((ext_vector_type(4))) float  float4v;  // MFMA C/D

__device__ __forceinline__ void wave_fence() {
    __asm__ volatile("s_waitcnt lgkmcnt(0)" ::: "memory");
}
__device__ __forceinline__ short bfbits(float f) {
    __hip_bfloat16 h = __float2bfloat16(f);
    return *reinterpret_cast<short*>(&h);
}

// ---------------------------------------------------------------------------
// Kernel 1: (a) q/k/v tables over the 520 distinct (t, token) combos,
// tab[(t*65+tok)*32 + h*8 + d], sqrt(C) folded into qtab (faithful bug);
// (b) lane-indexed bf16 weight-fragment table (7 classes x 64 lanes x short8);
// (c) zero-init of 16 line-padded loss slots.  NO fences anywhere.
// ---------------------------------------------------------------------------
__global__ void qkv_table_kernel(const float* __restrict__ tok_emb,
                                 const float* __restrict__ pos_emb,
                                 const float* __restrict__ Wq,
                                 const float* __restrict__ Wk,
                                 const float* __restrict__ Wv,
                                 const float* __restrict__ W_mlp,
                                 const float* __restrict__ W_lm,
                                 float* __restrict__ qtab,
                                 float* __restrict__ ktab,
                                 float* __restrict__ vtab,
                                 float* __restrict__ frag_tab,
                                 float* __restrict__ loss_slots) {
    int o = blockIdx.x * 256 + threadIdx.x;
    if (o < 16) loss_slots[o * 16] = 0.f;

    if (o < 3 * TABSZ) {
        int table = o / TABSZ;
        int r = o - table * TABSZ;
        int pair = r >> 5;
        int cd = r & 31;
        int t = pair / VOCAB;
        int tok = pair - t * VOCAB;
        int h = cd >> 3, d = cd & 7;
        const float* W = (table == 0) ? Wq : (table == 1) ? Wk : Wv;
        float acc = 0.f;
        #pragma unroll
        for (int c = 0; c < 32; ++c) {
            float xc = tok_emb[tok * 32 + c] + pos_emb[t * 32 + c];
            acc += xc * W[h * 256 + c * 8 + d];
        }
        if (table == 0) acc *= SQRT_C;   // faithful bug: scores * sqrt(C)
        float* tab = (table == 0) ? qtab : (table == 1) ? ktab : vtab;
        tab[r] = acc;
    } else if (o < 3 * TABSZ + NFRAG) {
        int f = o - 3 * TABSZ;
        int cls = f >> 6, lane = f & 63;
        int q4l = lane >> 4, nl = lane & 15;
        short8 v;
        #pragma unroll
        for (int j = 0; j < 8; ++j) {
            int k = q4l * 8 + j;
            if (cls < 2)       v[j] = bfbits(W_mlp[k * 32 + cls * 16 + nl]);
            else if (cls < 6)  v[j] = bfbits(W_lm[k * VOCAB + (cls - 2) * 16 + nl]);
            else               v[j] = (nl == 0) ? bfbits(W_lm[k * VOCAB + 64]) : (short)0;
        }
        ((short8*)frag_tab)[f] = v;
    }
}

// ---------------------------------------------------------------------------
// Kernel 2: one-shot throughput mode + fence-free loss (the untested
// quadrant).  Evidence: clean rounds show dur ~ 1/occupancy (R0 26%/188us,
// R4 18%/220us, R6 19%/239us); R5 proved 8192 one-shot blocks reach 71%
// occupancy but was poisoned by its __threadfence L2 writebacks (1022us =
// 797MB/780GBps exactly).  This round: one-shot structure, ZERO fences.
//  - 8192 blocks x 4 waves, one batch-pair per wave, no loop.
//  - LDS 17.5KB (x3 transpose buffer aliased onto dead sK region; ordering
//    enforced by data dependencies) -> 8 blocks/CU -> 32 waves/CU possible.
//  - Loss: wave reduce -> LDS -> one atomic per block into 16 padded slots.
// ---------------------------------------------------------------------------
__global__ __launch_bounds__(256, 8) void fused_kernel(
        const int* __restrict__ idx, const int* __restrict__ targets,
        const float* __restrict__ qtab, const float* __restrict__ ktab,
        const float* __restrict__ vtab,
        const float* __restrict__ frag_tab,
        const float* __restrict__ b_mlp,
        const float* __restrict__ b_lm,
        float* __restrict__ out_logits,
        float* __restrict__ loss_slots) {
    // per-wave K/V: [grp=h*2+b2][s][d], grp-stride 68 words (conflict-free
    // 8-group broadcast).  sX3 (640 shorts = 1280B) aliases sK (2176B/wave):
    // sK is dead once scores are computed; every sX3 write data-depends on
    // all sK/sV reads, so no reordering hazard exists.
    __shared__ __align__(16) float sK[4][544];
    __shared__ __align__(16) float sV[4][544];
    __shared__ float wsum[4];

    const int tid = threadIdx.x;
    const int w = tid >> 6, l = tid & 63;
    const int q4 = l >> 4;        // MFMA quad
    const int n  = l & 15;        // MFMA col-lane / A-row
    const int t  = l & 7, b2 = (l >> 3) & 1, h = q4;   // attention identity

    const int pb = blockIdx.x * 4 + w;

    // ---- tokens / targets (one 64B line per pair) ----
    int tokv = 0, tgv = 0;
    if (l < 16) { tokv = idx[pb * 16 + l]; tgv = targets[pb * 16 + l]; }

    // ---- prologue: 7 coalesced fragment loads + bias scalars ----
    const short8* ftab = (const short8*)frag_tab;
    short8 wmf[2], wlf[4], wlf4;
    wmf[0] = ftab[l];        wmf[1] = ftab[64 + l];
    #pragma unroll
    for (int c = 0; c < 4; ++c) wlf[c] = ftab[(2 + c) * 64 + l];
    wlf4 = ftab[6 * 64 + l];
    float bmc[2], blc[4];
    #pragma unroll
    for (int c = 0; c < 2; ++c) bmc[c] = b_mlp[c * 16 + n];
    #pragma unroll
    for (int c = 0; c < 4; ++c) blc[c] = b_lm[c * 16 + n];
    const float bl64 = b_lm[64];
    const float4v zf = {0.f, 0.f, 0.f, 0.f};

    // ---- gather K/V into LDS: 2 float4 chunks per table per lane ----
    #pragma unroll
    for (int half = 0; half < 2; ++half) {
        int c = l + half * 64;
        int d2 = c & 1, s = (c >> 1) & 7, grp = c >> 4;   // grp 0..7
        int b2g = grp & 1, hg = grp >> 1;
        int tok_s = __shfl(tokv, b2g * 8 + s);
        int gaddr = (s * VOCAB + tok_s) * 32 + hg * 8 + d2 * 4;
        int laddr = grp * 68 + s * 8 + d2 * 4;
        *(float4*)(&sK[w][laddr]) = *(const float4*)(ktab + gaddr);
        *(float4*)(&sV[w][laddr]) = *(const float4*)(vtab + gaddr);
    }
    // own q row (qtab already carries * sqrt(C))
    const int tok_t = __shfl(tokv, b2 * 8 + t);
    const float* qp = qtab + (t * VOCAB + tok_t) * 32 + h * 8;
    const float4 q0 = *(const float4*)(qp);
    const float4 q1 = *(const float4*)(qp + 4);
    // targets for my 4 epilogue rows
    int tgrc[4];
    #pragma unroll
    for (int i = 0; i < 4; ++i) tgrc[i] = __shfl(tgv, q4 * 4 + i);
    wave_fence();

    // ---- attention (fp32): lane (b2,h,t); out lands in MFMA A-layout ----
    const float* kb = &sK[w][(h * 2 + b2) * 68];
    const float* vb = &sV[w][(h * 2 + b2) * 68];
    float sc[8], m = -1e30f;
    #pragma unroll
    for (int s = 0; s < 8; ++s) {
        float4 k0 = *(const float4*)(kb + s * 8);
        float4 k1 = *(const float4*)(kb + s * 8 + 4);
        float d = q0.x * k0.x + q0.y * k0.y + q0.z * k0.z + q0.w * k0.w
                + q1.x * k1.x + q1.y * k1.y + q1.z * k1.z + q1.w * k1.w;
        sc[s] = d;
        if (s <= t) m = fmaxf(m, d);
    }
    float p[8], sum = 0.f;
    #pragma unroll
    for (int s = 0; s < 8; ++s) {
        p[s] = (s <= t) ? __expf(sc[s] - m) : 0.f;
        sum += p[s];
    }
    float inv = 1.f / sum;
    float o[8];
    #pragma unroll
    for (int d = 0; d < 8; ++d) o[d] = 0.f;
    #pragma unroll
    for (int s = 0; s < 8; ++s) {
        float4 v0 = *(const float4*)(vb + s * 8);
        float4 v1 = *(const float4*)(vb + s * 8 + 4);
        o[0] += p[s] * v0.x; o[1] += p[s] * v0.y;
        o[2] += p[s] * v0.z; o[3] += p[s] * v0.w;
        o[4] += p[s] * v1.x; o[5] += p[s] * v1.y;
        o[6] += p[s] * v1.z; o[7] += p[s] * v1.w;
    }
    short8 a2;
    #pragma unroll
    for (int d = 0; d < 8; ++d) a2[d] = bfbits(o[d] * inv);

    // ---- MLP: x3 = relu(x2 @ W_mlp + b), 2 MFMAs ----
    float4v d0 = __builtin_amdgcn_mfma_f32_16x16x32_bf16(a2, wmf[0], zf, 0, 0, 0);
    float4v d1 = __builtin_amdgcn_mfma_f32_16x16x32_bf16(a2, wmf[1], zf, 0, 0, 0);
    // x3 staged into the (now dead) sK region of this wave
    unsigned short* sx3 = (unsigned short*)(&sK[w][0]);
    #pragma unroll
    for (int i = 0; i < 4; ++i) {
        int row = q4 * 4 + i;
        sx3[row * 40 + n]      = (unsigned short)bfbits(fmaxf(d0[i] + bmc[0], 0.f));
        sx3[row * 40 + 16 + n] = (unsigned short)bfbits(fmaxf(d1[i] + bmc[1], 0.f));
    }
    wave_fence();
    // C->A transpose via LDS: one b128 read
    short8 a3 = *(const short8*)(&sx3[n * 40 + q4 * 8]);

    // ---- logits: 5 MFMAs (cols 0..63 + padded col-64 fragment) ----
    float4v Lc[4];
    #pragma unroll
    for (int c = 0; c < 4; ++c)
        Lc[c] = __builtin_amdgcn_mfma_f32_16x16x32_bf16(a3, wlf[c], zf, 0, 0, 0);
    float4v L64 = __builtin_amdgcn_mfma_f32_16x16x32_bf16(a3, wlf4, zf, 0, 0, 0);

    // ---- bias + scattered store + sum-exp + inline target pick ----
    float loss_local = 0.f;
    size_t rb = (size_t)pb * 16;
    float part[4] = {0.f, 0.f, 0.f, 0.f};
    #pragma unroll
    for (int c = 0; c < 4; ++c) {
        #pragma unroll
        for (int i = 0; i < 4; ++i) {
            float Lv = Lc[c][i] + blc[c];
            out_logits[(rb + q4 * 4 + i) * VOCAB + c * 16 + n] = Lv;
            part[i] += __expf(Lv);
            if (c * 16 + n == tgrc[i]) loss_local -= Lv;   // 1 lane/row
        }
    }
    if (n == 0) {
        #pragma unroll
        for (int i = 0; i < 4; ++i) {
            float Lv = L64[i] + bl64;
            out_logits[(rb + q4 * 4 + i) * VOCAB + 64] = Lv;
            part[i] += __expf(Lv);
            if (tgrc[i] == 64) loss_local -= Lv;
        }
    }
    #pragma unroll
    for (int off = 1; off < 16; off <<= 1) {
        #pragma unroll
        for (int i = 0; i < 4; ++i) part[i] += __shfl_xor(part[i], off);
    }
    if (n == 0)
        loss_local += __logf(part[0]) + __logf(part[1])
                    + __logf(part[2]) + __logf(part[3]);

    // ---- wave reduce -> block combine -> one slotted atomic (NO fence) ----
    #pragma unroll
    for (int off = 1; off < 64; off <<= 1) loss_local += __shfl_xor(loss_local, off);
    if (l == 0) wsum[w] = loss_local;
    __syncthreads();
    if (tid == 0)
        atomicAdd(&loss_slots[(blockIdx.x & 15) * 16],
                  wsum[0] + wsum[1] + wsum[2] + wsum[3]);
}

__global__ void finalize_loss(const float* __restrict__ slots,
                              float* __restrict__ out) {
    float tot = 0.f;
    #pragma unroll
    for (int s = 0; s < 16; ++s) tot += slots[s * 16];
    out[0] = tot * (1.f / (float)ROWS);
}

extern "C" void kernel_launch(void* const* d_in, const int* in_sizes, int n_in,
                              void* d_out, int out_size, void* d_ws, size_t ws_size,
                              hipStream_t stream) {
    const int* idx        = (const int*)d_in[0];
    const int* targets    = (const int*)d_in[1];
    const float* tok_emb  = (const float*)d_in[2];
    const float* pos_emb  = (const float*)d_in[3];
    const float* Wq       = (const float*)d_in[4];
    const float* Wk       = (const float*)d_in[5];
    const float* Wv       = (const float*)d_in[6];
    const float* W_mlp    = (const float*)d_in[7];
    const float* b_mlp    = (const float*)d_in[8];
    const float* W_lm     = (const float*)d_in[9];
    const float* b_lm     = (const float*)d_in[10];
    float* out            = (float*)d_out;

    float* ws         = (float*)d_ws;
    float* loss_slots = ws;                        // 16 slots, 64B apart
    float* frag       = ws + 256;                  // 448 short8 = 1792 floats
    float* qtab       = frag + 1792;
    float* ktab       = qtab + TABSZ;
    float* vtab       = ktab + TABSZ;
    float* out_loss   = out + (size_t)ROWS * VOCAB;

    qkv_table_kernel<<<(3 * TABSZ + NFRAG + 255) / 256, 256, 0, stream>>>(
        tok_emb, pos_emb, Wq, Wk, Wv, W_mlp, W_lm,
        qtab, ktab, vtab, frag, loss_slots);

    fused_kernel<<<NBLOCKS, 256, 0, stream>>>(
        idx, targets, qtab, ktab, vtab, frag, b_mlp, b_lm, out, loss_slots);

    finalize_loss<<<1, 1, 0, stream>>>(loss_slots, out_loss);
}